// Round 2
// baseline (713.459 us; speedup 1.0000x reference)
//
#include <hip/hip_runtime.h>
#include <cmath>

#define NN 100000
#define NE 1600000
#define FIN 128
#define HID 128
#define NCLS 40

// ---------------- CSR build ----------------

__global__ void hist_kernel(const int* __restrict__ dst, int* __restrict__ deg) {
    int e = blockIdx.x * blockDim.x + threadIdx.x;
    if (e < NE) atomicAdd(&deg[dst[e]], 1);
}

__global__ void dinv_kernel(const int* __restrict__ deg, float* __restrict__ dinv) {
    int i = blockIdx.x * blockDim.x + threadIdx.x;
    if (i < NN) dinv[i] = rsqrtf((float)(deg[i] + 1));  // +1 self-loop
}

// single-block exclusive scan of deg -> row_ptr (row_ptr[NN] = NE)
__global__ void scan_kernel(const int* __restrict__ deg, int* __restrict__ row_ptr) {
    __shared__ int part[1024];
    int tid = threadIdx.x;
    const int chunk = (NN + 1023) / 1024;
    int start = tid * chunk;
    int end = min(start + chunk, NN);
    int s = 0;
    for (int i = start; i < end; ++i) s += deg[i];
    part[tid] = s;
    __syncthreads();
    for (int off = 1; off < 1024; off <<= 1) {
        int add = (tid >= off) ? part[tid - off] : 0;
        __syncthreads();
        part[tid] += add;
        __syncthreads();
    }
    int base = (tid > 0) ? part[tid - 1] : 0;
    for (int i = start; i < end; ++i) { row_ptr[i] = base; base += deg[i]; }
    if (tid == 1023) row_ptr[NN] = part[1023];
}

__global__ void scatter_kernel(const int* __restrict__ src, const int* __restrict__ dst,
                               const int* __restrict__ row_ptr, int* __restrict__ cursor,
                               int* __restrict__ col) {
    int e = blockIdx.x * blockDim.x + threadIdx.x;
    if (e < NE) {
        int d = dst[e];
        int pos = row_ptr[d] + atomicAdd(&cursor[d], 1);
        col[pos] = src[e];
    }
}

// ---------------- GEMM1: hs = (x @ W1) * dinv[row] ----------------
// block: 256 threads, 32 rows x 128 cols per tile, thread = 4x4 register tile
__global__ __launch_bounds__(256) void gemm1_kernel(const float* __restrict__ x,
                                                    const float* __restrict__ W1,
                                                    const float* __restrict__ dinv,
                                                    float* __restrict__ hs) {
    __shared__ float wlds[FIN][HID];   // 64KB, [k][c]
    __shared__ float xlds[32][FIN];    // 16KB, [r][k]
    int tid = threadIdx.x;
    for (int i = tid; i < FIN * HID; i += 256) wlds[i / HID][i % HID] = W1[i];
    int ct = tid & 31;        // c0 = 4*ct
    int rt = tid >> 5;        // r0 = 4*rt (8 tiles -> 32 rows)
    int c0 = ct * 4;
    int nt = (NN + 31) / 32;
    for (int t = blockIdx.x; t < nt; t += gridDim.x) {
        int rowbase = t * 32;
        __syncthreads();
        for (int i = tid; i < 32 * (FIN / 4); i += 256) {
            int r = i / (FIN / 4);
            int k4 = i % (FIN / 4);
            int row = rowbase + r;
            float4 v = (row < NN) ? ((const float4*)x)[(size_t)row * (FIN / 4) + k4]
                                  : make_float4(0.f, 0.f, 0.f, 0.f);
            ((float4*)&xlds[r][0])[k4] = v;
        }
        __syncthreads();
        float acc[4][4];
#pragma unroll
        for (int a = 0; a < 4; ++a)
#pragma unroll
            for (int b = 0; b < 4; ++b) acc[a][b] = 0.f;
        for (int k = 0; k < FIN; k += 4) {
            float4 xv[4], wv[4];
#pragma unroll
            for (int a = 0; a < 4; ++a) xv[a] = *(const float4*)&xlds[rt * 4 + a][k];
#pragma unroll
            for (int kk = 0; kk < 4; ++kk) wv[kk] = *(const float4*)&wlds[k + kk][c0];
#pragma unroll
            for (int kk = 0; kk < 4; ++kk) {
                float4 w = wv[kk];
#pragma unroll
                for (int a = 0; a < 4; ++a) {
                    float xs = ((float*)&xv[a])[kk];
                    acc[a][0] = fmaf(xs, w.x, acc[a][0]);
                    acc[a][1] = fmaf(xs, w.y, acc[a][1]);
                    acc[a][2] = fmaf(xs, w.z, acc[a][2]);
                    acc[a][3] = fmaf(xs, w.w, acc[a][3]);
                }
            }
        }
#pragma unroll
        for (int a = 0; a < 4; ++a) {
            int row = rowbase + rt * 4 + a;
            if (row < NN) {
                float dv = dinv[row];
                float4 o = make_float4(acc[a][0] * dv, acc[a][1] * dv, acc[a][2] * dv,
                                       acc[a][3] * dv);
                ((float4*)hs)[(size_t)row * (HID / 4) + ct] = o;
            }
        }
    }
}

// ---------------- agg1: h1 = relu(dinv[i]*(hs[i] + sum_nbr hs) + b1) ----------------
// one wave (64 lanes) per node; 2 floats/lane (float2) = 128 features
__global__ __launch_bounds__(256) void agg1_kernel(const float* __restrict__ hs,
                                                   const int* __restrict__ row_ptr,
                                                   const int* __restrict__ col,
                                                   const float* __restrict__ dinv,
                                                   const float* __restrict__ b1,
                                                   float* __restrict__ h1) {
    int wave = (blockIdx.x * blockDim.x + threadIdx.x) >> 6;
    int lane = threadIdx.x & 63;
    int nwaves = (gridDim.x * blockDim.x) >> 6;
    float2 bb = ((const float2*)b1)[lane];
    for (int i = wave; i < NN; i += nwaves) {
        float2 acc = ((const float2*)hs)[(size_t)i * 64 + lane];  // self term
        int e = row_ptr[i], s1 = row_ptr[i + 1];
        for (; e + 4 <= s1; e += 4) {
            int sa = col[e + 0], sb = col[e + 1], sc = col[e + 2], sd = col[e + 3];
            float2 va = ((const float2*)hs)[(size_t)sa * 64 + lane];
            float2 vb = ((const float2*)hs)[(size_t)sb * 64 + lane];
            float2 vc = ((const float2*)hs)[(size_t)sc * 64 + lane];
            float2 vd = ((const float2*)hs)[(size_t)sd * 64 + lane];
            acc.x += va.x + vb.x + vc.x + vd.x;
            acc.y += va.y + vb.y + vc.y + vd.y;
        }
        for (; e < s1; ++e) {
            int s = col[e];
            float2 v = ((const float2*)hs)[(size_t)s * 64 + lane];
            acc.x += v.x;
            acc.y += v.y;
        }
        float dv = dinv[i];
        float ox = fmaxf(fmaf(acc.x, dv, bb.x), 0.f);
        float oy = fmaxf(fmaf(acc.y, dv, bb.y), 0.f);
        ((float2*)h1)[(size_t)i * 64 + lane] = make_float2(ox, oy);
    }
}

// ---------------- GEMM2: hs2 = (h1 @ W2) * dinv[row], cols padded 40->64 ----------------
__global__ __launch_bounds__(256) void gemm2_kernel(const float* __restrict__ h1,
                                                    const float* __restrict__ W2,
                                                    const float* __restrict__ dinv,
                                                    float* __restrict__ hs2) {
    __shared__ float wlds[HID][64];   // 32KB zero-padded
    __shared__ float xlds[64][HID];   // 32KB
    int tid = threadIdx.x;
    for (int i = tid; i < HID * 64; i += 256) {
        int k = i / 64, c = i % 64;
        wlds[k][c] = (c < NCLS) ? W2[k * NCLS + c] : 0.f;
    }
    int ct = tid & 15;   // c0 = 4*ct (0..60)
    int rt = tid >> 4;   // 0..15 -> 64 rows
    int c0 = ct * 4;
    int nt = (NN + 63) / 64;
    for (int t = blockIdx.x; t < nt; t += gridDim.x) {
        int rowbase = t * 64;
        __syncthreads();
        for (int i = tid; i < 64 * (HID / 4); i += 256) {
            int r = i / (HID / 4);
            int k4 = i % (HID / 4);
            int row = rowbase + r;
            float4 v = (row < NN) ? ((const float4*)h1)[(size_t)row * (HID / 4) + k4]
                                  : make_float4(0.f, 0.f, 0.f, 0.f);
            ((float4*)&xlds[r][0])[k4] = v;
        }
        __syncthreads();
        float acc[4][4];
#pragma unroll
        for (int a = 0; a < 4; ++a)
#pragma unroll
            for (int b = 0; b < 4; ++b) acc[a][b] = 0.f;
        for (int k = 0; k < HID; k += 4) {
            float4 xv[4], wv[4];
#pragma unroll
            for (int a = 0; a < 4; ++a) xv[a] = *(const float4*)&xlds[rt * 4 + a][k];
#pragma unroll
            for (int kk = 0; kk < 4; ++kk) wv[kk] = *(const float4*)&wlds[k + kk][c0];
#pragma unroll
            for (int kk = 0; kk < 4; ++kk) {
                float4 w = wv[kk];
#pragma unroll
                for (int a = 0; a < 4; ++a) {
                    float xs = ((float*)&xv[a])[kk];
                    acc[a][0] = fmaf(xs, w.x, acc[a][0]);
                    acc[a][1] = fmaf(xs, w.y, acc[a][1]);
                    acc[a][2] = fmaf(xs, w.z, acc[a][2]);
                    acc[a][3] = fmaf(xs, w.w, acc[a][3]);
                }
            }
        }
        if (c0 < NCLS) {
#pragma unroll
            for (int a = 0; a < 4; ++a) {
                int row = rowbase + rt * 4 + a;
                if (row < NN) {
                    float dv = dinv[row];
                    float4 o = make_float4(acc[a][0] * dv, acc[a][1] * dv, acc[a][2] * dv,
                                           acc[a][3] * dv);
                    *(float4*)(hs2 + (size_t)row * NCLS + c0) = o;
                }
            }
        }
    }
}

// ---------------- agg2 + bias + log_softmax ----------------
// one wave per node; lanes 0..39 hold one class each
__global__ __launch_bounds__(256) void agg2_kernel(const float* __restrict__ hs2,
                                                   const int* __restrict__ row_ptr,
                                                   const int* __restrict__ col,
                                                   const float* __restrict__ dinv,
                                                   const float* __restrict__ b2,
                                                   float* __restrict__ out) {
    int wave = (blockIdx.x * blockDim.x + threadIdx.x) >> 6;
    int lane = threadIdx.x & 63;
    int nwaves = (gridDim.x * blockDim.x) >> 6;
    bool act = lane < NCLS;
    float bias = act ? b2[lane] : 0.f;
    for (int i = wave; i < NN; i += nwaves) {
        float acc = act ? hs2[(size_t)i * NCLS + lane] : 0.f;
        int e = row_ptr[i], s1 = row_ptr[i + 1];
        for (; e + 4 <= s1; e += 4) {
            int sa = col[e + 0], sb = col[e + 1], sc = col[e + 2], sd = col[e + 3];
            if (act) {
                float va = hs2[(size_t)sa * NCLS + lane];
                float vb = hs2[(size_t)sb * NCLS + lane];
                float vc = hs2[(size_t)sc * NCLS + lane];
                float vd = hs2[(size_t)sd * NCLS + lane];
                acc += va + vb + vc + vd;
            }
        }
        for (; e < s1; ++e) {
            int s = col[e];
            if (act) acc += hs2[(size_t)s * NCLS + lane];
        }
        float logit = act ? fmaf(acc, dinv[i], bias) : -INFINITY;
        float m = logit;
#pragma unroll
        for (int off = 32; off; off >>= 1) m = fmaxf(m, __shfl_xor(m, off));
        float ex = act ? expf(logit - m) : 0.f;
        float ssum = ex;
#pragma unroll
        for (int off = 32; off; off >>= 1) ssum += __shfl_xor(ssum, off);
        if (act) out[(size_t)i * NCLS + lane] = (logit - m) - logf(ssum);
    }
}

extern "C" void kernel_launch(void* const* d_in, const int* in_sizes, int n_in,
                              void* d_out, int out_size, void* d_ws, size_t ws_size,
                              hipStream_t stream) {
    const float* x = (const float*)d_in[0];
    const int* edge_index = (const int*)d_in[1];
    const float* W1 = (const float*)d_in[2];
    const float* b1 = (const float*)d_in[3];
    const float* W2 = (const float*)d_in[4];
    const float* b2 = (const float*)d_in[5];
    float* out = (float*)d_out;
    const int* src = edge_index;          // edge_index[0]
    const int* dst = edge_index + NE;     // edge_index[1]

    char* ws = (char*)d_ws;
    size_t off = 0;
    auto alloc = [&](size_t bytes) -> void* {
        void* p = (void*)(ws + off);
        off += (bytes + 255) & ~(size_t)255;
        return p;
    };
    int* deg = (int*)alloc((size_t)NN * 4);
    int* cursor = (int*)alloc((size_t)NN * 4);
    int* row_ptr = (int*)alloc((size_t)(NN + 1) * 4);
    int* col = (int*)alloc((size_t)NE * 4);
    float* dinv = (float*)alloc((size_t)NN * 4);
    float* hs = (float*)alloc((size_t)NN * HID * 4);
    float* h1 = (float*)alloc((size_t)NN * HID * 4);
    float* hs2 = hs;  // reuse hs buffer after agg1 consumed it

    hipMemsetAsync(deg, 0, (size_t)NN * 4, stream);
    hipMemsetAsync(cursor, 0, (size_t)NN * 4, stream);

    hist_kernel<<<(NE + 255) / 256, 256, 0, stream>>>(dst, deg);
    dinv_kernel<<<(NN + 255) / 256, 256, 0, stream>>>(deg, dinv);
    scan_kernel<<<1, 1024, 0, stream>>>(deg, row_ptr);
    scatter_kernel<<<(NE + 255) / 256, 256, 0, stream>>>(src, dst, row_ptr, cursor, col);
    gemm1_kernel<<<512, 256, 0, stream>>>(x, W1, dinv, hs);
    agg1_kernel<<<2048, 256, 0, stream>>>(hs, row_ptr, col, dinv, b1, h1);
    gemm2_kernel<<<512, 256, 0, stream>>>(h1, W2, dinv, hs2);
    agg2_kernel<<<2048, 256, 0, stream>>>(hs2, row_ptr, col, dinv, b2, out);
}

// Round 4
// 550.854 us; speedup vs baseline: 1.2952x; 1.2952x over previous
//
#include <hip/hip_runtime.h>
#include <cmath>

#define NN 100000
#define NE 1600000
#define FIN 128
#define HID 128
#define NCLS 40

#define SCAN_BPB 1024                      // elements per block in the scan
#define SCAN_NB ((NN + SCAN_BPB - 1) / SCAN_BPB)   // 98 blocks

// ---------------- CSR build ----------------

__global__ void hist_kernel(const int* __restrict__ dst, int* __restrict__ deg) {
    int e = blockIdx.x * blockDim.x + threadIdx.x;
    if (e < NE) atomicAdd(&deg[dst[e]], 1);
}

__global__ void dinv_kernel(const int* __restrict__ deg, float* __restrict__ dinv) {
    int i = blockIdx.x * blockDim.x + threadIdx.x;
    if (i < NN) dinv[i] = rsqrtf((float)(deg[i] + 1));  // +1 self-loop
}

// --- 3-phase parallel exclusive scan of deg -> row_ptr ---
// phase 1: per-block local exclusive scan (4 elems/thread, int4), block total -> bsum
__global__ __launch_bounds__(256) void scan1_kernel(const int* __restrict__ deg,
                                                    int* __restrict__ row_ptr,
                                                    int* __restrict__ bsum) {
    __shared__ int tsum[256];
    int tid = threadIdx.x;
    int base = blockIdx.x * SCAN_BPB + tid * 4;
    int4 v = make_int4(0, 0, 0, 0);
    if (base + 3 < NN) {
        v = *(const int4*)(deg + base);
    } else {
        if (base + 0 < NN) v.x = deg[base + 0];
        if (base + 1 < NN) v.y = deg[base + 1];
        if (base + 2 < NN) v.z = deg[base + 2];
        if (base + 3 < NN) v.w = deg[base + 3];
    }
    int s = v.x + v.y + v.z + v.w;
    tsum[tid] = s;
    __syncthreads();
    for (int off = 1; off < 256; off <<= 1) {
        int add = (tid >= off) ? tsum[tid - off] : 0;
        __syncthreads();
        tsum[tid] += add;
        __syncthreads();
    }
    int ex = tsum[tid] - s;  // exclusive offset within block
    if (base + 0 < NN) row_ptr[base + 0] = ex;
    ex += v.x;
    if (base + 1 < NN) row_ptr[base + 1] = ex;
    ex += v.y;
    if (base + 2 < NN) row_ptr[base + 2] = ex;
    ex += v.z;
    if (base + 3 < NN) row_ptr[base + 3] = ex;
    if (tid == 255) bsum[blockIdx.x] = tsum[255];
}

// phase 2: single tiny block scans the 98 block sums (in place, exclusive)
__global__ void scan2_kernel(int* __restrict__ bsum) {
    __shared__ int tmp[128];
    int tid = threadIdx.x;
    int v = (tid < SCAN_NB) ? bsum[tid] : 0;
    tmp[tid] = v;
    __syncthreads();
    for (int off = 1; off < 128; off <<= 1) {
        int add = (tid >= off) ? tmp[tid - off] : 0;
        __syncthreads();
        tmp[tid] += add;
        __syncthreads();
    }
    if (tid < SCAN_NB) bsum[tid] = tmp[tid] - v;  // exclusive
}

// phase 3: add block offsets; also write row_ptr[NN] = NE
__global__ __launch_bounds__(256) void scan3_kernel(int* __restrict__ row_ptr,
                                                    const int* __restrict__ bsum) {
    int off = bsum[blockIdx.x];
    int base = blockIdx.x * SCAN_BPB + threadIdx.x * 4;
    if (base + 3 < NN) {
        int4 v = *(int4*)(row_ptr + base);
        v.x += off; v.y += off; v.z += off; v.w += off;
        *(int4*)(row_ptr + base) = v;
    } else {
#pragma unroll
        for (int j = 0; j < 4; ++j)
            if (base + j < NN) row_ptr[base + j] += off;
    }
    if (blockIdx.x == 0 && threadIdx.x == 0) row_ptr[NN] = NE;
}

__global__ void scatter_kernel(const int* __restrict__ src, const int* __restrict__ dst,
                               const int* __restrict__ row_ptr, int* __restrict__ cursor,
                               int* __restrict__ col) {
    int e = blockIdx.x * blockDim.x + threadIdx.x;
    if (e < NE) {
        int d = dst[e];
        int pos = row_ptr[d] + atomicAdd(&cursor[d], 1);
        col[pos] = src[e];
    }
}

// ---------------- GEMM1: hs = (x @ W1) * dinv[row] ----------------
// block: 256 threads, 32 rows x 128 cols per tile, thread = 4x4 register tile
__global__ __launch_bounds__(256) void gemm1_kernel(const float* __restrict__ x,
                                                    const float* __restrict__ W1,
                                                    const float* __restrict__ dinv,
                                                    float* __restrict__ hs) {
    __shared__ float wlds[FIN][HID];   // 64KB, [k][c]
    __shared__ float xlds[32][FIN];    // 16KB, [r][k]
    int tid = threadIdx.x;
    for (int i = tid; i < FIN * HID; i += 256) wlds[i / HID][i % HID] = W1[i];
    int ct = tid & 31;        // c0 = 4*ct
    int rt = tid >> 5;        // r0 = 4*rt (8 tiles -> 32 rows)
    int c0 = ct * 4;
    int nt = (NN + 31) / 32;
    for (int t = blockIdx.x; t < nt; t += gridDim.x) {
        int rowbase = t * 32;
        __syncthreads();
        for (int i = tid; i < 32 * (FIN / 4); i += 256) {
            int r = i / (FIN / 4);
            int k4 = i % (FIN / 4);
            int row = rowbase + r;
            float4 v = (row < NN) ? ((const float4*)x)[(size_t)row * (FIN / 4) + k4]
                                  : make_float4(0.f, 0.f, 0.f, 0.f);
            ((float4*)&xlds[r][0])[k4] = v;
        }
        __syncthreads();
        float acc[4][4];
#pragma unroll
        for (int a = 0; a < 4; ++a)
#pragma unroll
            for (int b = 0; b < 4; ++b) acc[a][b] = 0.f;
        for (int k = 0; k < FIN; k += 4) {
            float4 xv[4], wv[4];
#pragma unroll
            for (int a = 0; a < 4; ++a) xv[a] = *(const float4*)&xlds[rt * 4 + a][k];
#pragma unroll
            for (int kk = 0; kk < 4; ++kk) wv[kk] = *(const float4*)&wlds[k + kk][c0];
#pragma unroll
            for (int kk = 0; kk < 4; ++kk) {
                float4 w = wv[kk];
#pragma unroll
                for (int a = 0; a < 4; ++a) {
                    float xs = ((float*)&xv[a])[kk];
                    acc[a][0] = fmaf(xs, w.x, acc[a][0]);
                    acc[a][1] = fmaf(xs, w.y, acc[a][1]);
                    acc[a][2] = fmaf(xs, w.z, acc[a][2]);
                    acc[a][3] = fmaf(xs, w.w, acc[a][3]);
                }
            }
        }
#pragma unroll
        for (int a = 0; a < 4; ++a) {
            int row = rowbase + rt * 4 + a;
            if (row < NN) {
                float dv = dinv[row];
                float4 o = make_float4(acc[a][0] * dv, acc[a][1] * dv, acc[a][2] * dv,
                                       acc[a][3] * dv);
                ((float4*)hs)[(size_t)row * (HID / 4) + ct] = o;
            }
        }
    }
}

// ---------------- agg1: h1 = relu(dinv[i]*(hs[i] + sum_nbr hs) + b1) ----------------
// one wave (64 lanes) per node; 2 floats/lane (float2) = 128 features
__global__ __launch_bounds__(256) void agg1_kernel(const float* __restrict__ hs,
                                                   const int* __restrict__ row_ptr,
                                                   const int* __restrict__ col,
                                                   const float* __restrict__ dinv,
                                                   const float* __restrict__ b1,
                                                   float* __restrict__ h1) {
    int wave = (blockIdx.x * blockDim.x + threadIdx.x) >> 6;
    int lane = threadIdx.x & 63;
    int nwaves = (gridDim.x * blockDim.x) >> 6;
    float2 bb = ((const float2*)b1)[lane];
    for (int i = wave; i < NN; i += nwaves) {
        float2 acc = ((const float2*)hs)[(size_t)i * 64 + lane];  // self term
        int e = row_ptr[i], s1 = row_ptr[i + 1];
        for (; e + 4 <= s1; e += 4) {
            int sa = col[e + 0], sb = col[e + 1], sc = col[e + 2], sd = col[e + 3];
            float2 va = ((const float2*)hs)[(size_t)sa * 64 + lane];
            float2 vb = ((const float2*)hs)[(size_t)sb * 64 + lane];
            float2 vc = ((const float2*)hs)[(size_t)sc * 64 + lane];
            float2 vd = ((const float2*)hs)[(size_t)sd * 64 + lane];
            acc.x += va.x + vb.x + vc.x + vd.x;
            acc.y += va.y + vb.y + vc.y + vd.y;
        }
        for (; e < s1; ++e) {
            int s = col[e];
            float2 v = ((const float2*)hs)[(size_t)s * 64 + lane];
            acc.x += v.x;
            acc.y += v.y;
        }
        float dv = dinv[i];
        float ox = fmaxf(fmaf(acc.x, dv, bb.x), 0.f);
        float oy = fmaxf(fmaf(acc.y, dv, bb.y), 0.f);
        ((float2*)h1)[(size_t)i * 64 + lane] = make_float2(ox, oy);
    }
}

// ---------------- GEMM2: hs2 = (h1 @ W2) * dinv[row], cols padded 40->64 ----------------
__global__ __launch_bounds__(256) void gemm2_kernel(const float* __restrict__ h1,
                                                    const float* __restrict__ W2,
                                                    const float* __restrict__ dinv,
                                                    float* __restrict__ hs2) {
    __shared__ float wlds[HID][64];   // 32KB zero-padded
    __shared__ float xlds[64][HID];   // 32KB
    int tid = threadIdx.x;
    for (int i = tid; i < HID * 64; i += 256) {
        int k = i / 64, c = i % 64;
        wlds[k][c] = (c < NCLS) ? W2[k * NCLS + c] : 0.f;
    }
    int ct = tid & 15;   // c0 = 4*ct (0..60)
    int rt = tid >> 4;   // 0..15 -> 64 rows
    int c0 = ct * 4;
    int nt = (NN + 63) / 64;
    for (int t = blockIdx.x; t < nt; t += gridDim.x) {
        int rowbase = t * 64;
        __syncthreads();
        for (int i = tid; i < 64 * (HID / 4); i += 256) {
            int r = i / (HID / 4);
            int k4 = i % (HID / 4);
            int row = rowbase + r;
            float4 v = (row < NN) ? ((const float4*)h1)[(size_t)row * (HID / 4) + k4]
                                  : make_float4(0.f, 0.f, 0.f, 0.f);
            ((float4*)&xlds[r][0])[k4] = v;
        }
        __syncthreads();
        float acc[4][4];
#pragma unroll
        for (int a = 0; a < 4; ++a)
#pragma unroll
            for (int b = 0; b < 4; ++b) acc[a][b] = 0.f;
        for (int k = 0; k < HID; k += 4) {
            float4 xv[4], wv[4];
#pragma unroll
            for (int a = 0; a < 4; ++a) xv[a] = *(const float4*)&xlds[rt * 4 + a][k];
#pragma unroll
            for (int kk = 0; kk < 4; ++kk) wv[kk] = *(const float4*)&wlds[k + kk][c0];
#pragma unroll
            for (int kk = 0; kk < 4; ++kk) {
                float4 w = wv[kk];
#pragma unroll
                for (int a = 0; a < 4; ++a) {
                    float xs = ((float*)&xv[a])[kk];
                    acc[a][0] = fmaf(xs, w.x, acc[a][0]);
                    acc[a][1] = fmaf(xs, w.y, acc[a][1]);
                    acc[a][2] = fmaf(xs, w.z, acc[a][2]);
                    acc[a][3] = fmaf(xs, w.w, acc[a][3]);
                }
            }
        }
        if (c0 < NCLS) {
#pragma unroll
            for (int a = 0; a < 4; ++a) {
                int row = rowbase + rt * 4 + a;
                if (row < NN) {
                    float dv = dinv[row];
                    float4 o = make_float4(acc[a][0] * dv, acc[a][1] * dv, acc[a][2] * dv,
                                           acc[a][3] * dv);
                    *(float4*)(hs2 + (size_t)row * NCLS + c0) = o;
                }
            }
        }
    }
}

// ---------------- agg2 + bias + log_softmax ----------------
// one wave per node; lanes 0..39 hold one class each
__global__ __launch_bounds__(256) void agg2_kernel(const float* __restrict__ hs2,
                                                   const int* __restrict__ row_ptr,
                                                   const int* __restrict__ col,
                                                   const float* __restrict__ dinv,
                                                   const float* __restrict__ b2,
                                                   float* __restrict__ out) {
    int wave = (blockIdx.x * blockDim.x + threadIdx.x) >> 6;
    int lane = threadIdx.x & 63;
    int nwaves = (gridDim.x * blockDim.x) >> 6;
    bool act = lane < NCLS;
    float bias = act ? b2[lane] : 0.f;
    for (int i = wave; i < NN; i += nwaves) {
        float acc = act ? hs2[(size_t)i * NCLS + lane] : 0.f;
        int e = row_ptr[i], s1 = row_ptr[i + 1];
        for (; e + 4 <= s1; e += 4) {
            int sa = col[e + 0], sb = col[e + 1], sc = col[e + 2], sd = col[e + 3];
            if (act) {
                float va = hs2[(size_t)sa * NCLS + lane];
                float vb = hs2[(size_t)sb * NCLS + lane];
                float vc = hs2[(size_t)sc * NCLS + lane];
                float vd = hs2[(size_t)sd * NCLS + lane];
                acc += va + vb + vc + vd;
            }
        }
        for (; e < s1; ++e) {
            int s = col[e];
            if (act) acc += hs2[(size_t)s * NCLS + lane];
        }
        float logit = act ? fmaf(acc, dinv[i], bias) : -INFINITY;
        float m = logit;
#pragma unroll
        for (int off = 32; off; off >>= 1) m = fmaxf(m, __shfl_xor(m, off));
        float ex = act ? expf(logit - m) : 0.f;
        float ssum = ex;
#pragma unroll
        for (int off = 32; off; off >>= 1) ssum += __shfl_xor(ssum, off);
        if (act) out[(size_t)i * NCLS + lane] = (logit - m) - logf(ssum);
    }
}

extern "C" void kernel_launch(void* const* d_in, const int* in_sizes, int n_in,
                              void* d_out, int out_size, void* d_ws, size_t ws_size,
                              hipStream_t stream) {
    const float* x = (const float*)d_in[0];
    const int* edge_index = (const int*)d_in[1];
    const float* W1 = (const float*)d_in[2];
    const float* b1 = (const float*)d_in[3];
    const float* W2 = (const float*)d_in[4];
    const float* b2 = (const float*)d_in[5];
    float* out = (float*)d_out;
    const int* src = edge_index;          // edge_index[0]
    const int* dst = edge_index + NE;     // edge_index[1]

    char* ws = (char*)d_ws;
    size_t off = 0;
    auto alloc = [&](size_t bytes) -> void* {
        void* p = (void*)(ws + off);
        off += (bytes + 255) & ~(size_t)255;
        return p;
    };
    int* deg = (int*)alloc((size_t)NN * 4);
    int* cursor = (int*)alloc((size_t)NN * 4);
    int* row_ptr = (int*)alloc((size_t)(NN + 1) * 4);
    int* col = (int*)alloc((size_t)NE * 4);
    int* bsum = (int*)alloc((size_t)SCAN_NB * 4);
    float* dinv = (float*)alloc((size_t)NN * 4);
    float* hs = (float*)alloc((size_t)NN * HID * 4);
    float* h1 = (float*)alloc((size_t)NN * HID * 4);
    float* hs2 = hs;  // reuse hs buffer after agg1 consumed it

    hipMemsetAsync(deg, 0, (size_t)NN * 4, stream);
    hipMemsetAsync(cursor, 0, (size_t)NN * 4, stream);

    hist_kernel<<<(NE + 255) / 256, 256, 0, stream>>>(dst, deg);
    dinv_kernel<<<(NN + 255) / 256, 256, 0, stream>>>(deg, dinv);
    scan1_kernel<<<SCAN_NB, 256, 0, stream>>>(deg, row_ptr, bsum);
    scan2_kernel<<<1, 128, 0, stream>>>(bsum);
    scan3_kernel<<<SCAN_NB, 256, 0, stream>>>(row_ptr, bsum);
    scatter_kernel<<<(NE + 255) / 256, 256, 0, stream>>>(src, dst, row_ptr, cursor, col);
    gemm1_kernel<<<512, 256, 0, stream>>>(x, W1, dinv, hs);
    agg1_kernel<<<2048, 256, 0, stream>>>(hs, row_ptr, col, dinv, b1, h1);
    gemm2_kernel<<<512, 256, 0, stream>>>(h1, W2, dinv, hs2);
    agg2_kernel<<<2048, 256, 0, stream>>>(hs2, row_ptr, col, dinv, b2, out);
}

// Round 5
// 504.313 us; speedup vs baseline: 1.4147x; 1.0923x over previous
//
#include <hip/hip_runtime.h>
#include <cmath>

#define NN 100000
#define NE 1600000
#define FIN 128
#define HID 128
#define NCLS 40

#define SCAN_BPB 1024                      // elements per block in the scan
#define SCAN_NB ((NN + SCAN_BPB - 1) / SCAN_BPB)   // 98 blocks

// ---- packed bf16 helpers (RNE) ----
__device__ __forceinline__ unsigned pk_bf16(float a, float b) {
    unsigned ua = __float_as_uint(a);
    unsigned ub = __float_as_uint(b);
    ua += 0x7FFFu + ((ua >> 16) & 1u);
    ub += 0x7FFFu + ((ub >> 16) & 1u);
    return (ua >> 16) | (ub & 0xFFFF0000u);
}
__device__ __forceinline__ float2 upk_bf16(unsigned u) {
    return make_float2(__uint_as_float(u << 16), __uint_as_float(u & 0xFFFF0000u));
}

// ---------------- CSR build ----------------

__global__ void hist_kernel(const int* __restrict__ dst, int* __restrict__ deg) {
    int e = blockIdx.x * blockDim.x + threadIdx.x;
    if (e < NE) atomicAdd(&deg[dst[e]], 1);
}

__global__ void dinv_kernel(const int* __restrict__ deg, float* __restrict__ dinv) {
    int i = blockIdx.x * blockDim.x + threadIdx.x;
    if (i < NN) dinv[i] = rsqrtf((float)(deg[i] + 1));  // +1 self-loop
}

// --- 3-phase parallel exclusive scan of deg -> row_ptr ---
__global__ __launch_bounds__(256) void scan1_kernel(const int* __restrict__ deg,
                                                    int* __restrict__ row_ptr,
                                                    int* __restrict__ bsum) {
    __shared__ int tsum[256];
    int tid = threadIdx.x;
    int base = blockIdx.x * SCAN_BPB + tid * 4;
    int4 v = make_int4(0, 0, 0, 0);
    if (base + 3 < NN) {
        v = *(const int4*)(deg + base);
    } else {
        if (base + 0 < NN) v.x = deg[base + 0];
        if (base + 1 < NN) v.y = deg[base + 1];
        if (base + 2 < NN) v.z = deg[base + 2];
        if (base + 3 < NN) v.w = deg[base + 3];
    }
    int s = v.x + v.y + v.z + v.w;
    tsum[tid] = s;
    __syncthreads();
    for (int off = 1; off < 256; off <<= 1) {
        int add = (tid >= off) ? tsum[tid - off] : 0;
        __syncthreads();
        tsum[tid] += add;
        __syncthreads();
    }
    int ex = tsum[tid] - s;
    if (base + 0 < NN) row_ptr[base + 0] = ex;
    ex += v.x;
    if (base + 1 < NN) row_ptr[base + 1] = ex;
    ex += v.y;
    if (base + 2 < NN) row_ptr[base + 2] = ex;
    ex += v.z;
    if (base + 3 < NN) row_ptr[base + 3] = ex;
    if (tid == 255) bsum[blockIdx.x] = tsum[255];
}

__global__ void scan2_kernel(int* __restrict__ bsum) {
    __shared__ int tmp[128];
    int tid = threadIdx.x;
    int v = (tid < SCAN_NB) ? bsum[tid] : 0;
    tmp[tid] = v;
    __syncthreads();
    for (int off = 1; off < 128; off <<= 1) {
        int add = (tid >= off) ? tmp[tid - off] : 0;
        __syncthreads();
        tmp[tid] += add;
        __syncthreads();
    }
    if (tid < SCAN_NB) bsum[tid] = tmp[tid] - v;
}

__global__ __launch_bounds__(256) void scan3_kernel(int* __restrict__ row_ptr,
                                                    const int* __restrict__ bsum) {
    int off = bsum[blockIdx.x];
    int base = blockIdx.x * SCAN_BPB + threadIdx.x * 4;
    if (base + 3 < NN) {
        int4 v = *(int4*)(row_ptr + base);
        v.x += off; v.y += off; v.z += off; v.w += off;
        *(int4*)(row_ptr + base) = v;
    } else {
#pragma unroll
        for (int j = 0; j < 4; ++j)
            if (base + j < NN) row_ptr[base + j] += off;
    }
    if (blockIdx.x == 0 && threadIdx.x == 0) row_ptr[NN] = NE;
}

__global__ void scatter_kernel(const int* __restrict__ src, const int* __restrict__ dst,
                               const int* __restrict__ row_ptr, int* __restrict__ cursor,
                               int* __restrict__ col) {
    int e = blockIdx.x * blockDim.x + threadIdx.x;
    if (e < NE) {
        int d = dst[e];
        int pos = row_ptr[d] + atomicAdd(&cursor[d], 1);
        col[pos] = src[e];
    }
}

// ---------------- GEMM1: hsb = bf16((x @ W1) * dinv[row]) ----------------
__global__ __launch_bounds__(256) void gemm1_kernel(const float* __restrict__ x,
                                                    const float* __restrict__ W1,
                                                    const float* __restrict__ dinv,
                                                    unsigned* __restrict__ hsb) {
    __shared__ float wlds[FIN][HID];   // 64KB, [k][c]
    __shared__ float xlds[32][FIN];    // 16KB, [r][k]
    int tid = threadIdx.x;
    for (int i = tid; i < FIN * HID; i += 256) wlds[i / HID][i % HID] = W1[i];
    int ct = tid & 31;        // c0 = 4*ct
    int rt = tid >> 5;        // r0 = 4*rt (8 tiles -> 32 rows)
    int c0 = ct * 4;
    int nt = (NN + 31) / 32;
    for (int t = blockIdx.x; t < nt; t += gridDim.x) {
        int rowbase = t * 32;
        __syncthreads();
        for (int i = tid; i < 32 * (FIN / 4); i += 256) {
            int r = i / (FIN / 4);
            int k4 = i % (FIN / 4);
            int row = rowbase + r;
            float4 v = (row < NN) ? ((const float4*)x)[(size_t)row * (FIN / 4) + k4]
                                  : make_float4(0.f, 0.f, 0.f, 0.f);
            ((float4*)&xlds[r][0])[k4] = v;
        }
        __syncthreads();
        float acc[4][4];
#pragma unroll
        for (int a = 0; a < 4; ++a)
#pragma unroll
            for (int b = 0; b < 4; ++b) acc[a][b] = 0.f;
        for (int k = 0; k < FIN; k += 4) {
            float4 xv[4], wv[4];
#pragma unroll
            for (int a = 0; a < 4; ++a) xv[a] = *(const float4*)&xlds[rt * 4 + a][k];
#pragma unroll
            for (int kk = 0; kk < 4; ++kk) wv[kk] = *(const float4*)&wlds[k + kk][c0];
#pragma unroll
            for (int kk = 0; kk < 4; ++kk) {
                float4 w = wv[kk];
#pragma unroll
                for (int a = 0; a < 4; ++a) {
                    float xs = ((float*)&xv[a])[kk];
                    acc[a][0] = fmaf(xs, w.x, acc[a][0]);
                    acc[a][1] = fmaf(xs, w.y, acc[a][1]);
                    acc[a][2] = fmaf(xs, w.z, acc[a][2]);
                    acc[a][3] = fmaf(xs, w.w, acc[a][3]);
                }
            }
        }
#pragma unroll
        for (int a = 0; a < 4; ++a) {
            int row = rowbase + rt * 4 + a;
            if (row < NN) {
                float dv = dinv[row];
                uint2 o = make_uint2(pk_bf16(acc[a][0] * dv, acc[a][1] * dv),
                                     pk_bf16(acc[a][2] * dv, acc[a][3] * dv));
                *(uint2*)(hsb + (size_t)row * 64 + ct * 2) = o;
            }
        }
    }
}

// ---------------- agg1: h1b = bf16(relu(dinv[i]*(hs[i] + sum_nbr hs) + b1)) ----------------
// one wave per node; lane owns features 2*lane, 2*lane+1 (one packed dword)
__global__ __launch_bounds__(256) void agg1_kernel(const unsigned* __restrict__ hsb,
                                                   const int* __restrict__ row_ptr,
                                                   const int* __restrict__ col,
                                                   const float* __restrict__ dinv,
                                                   const float* __restrict__ b1,
                                                   unsigned* __restrict__ h1b) {
    int wave = (blockIdx.x * blockDim.x + threadIdx.x) >> 6;
    int lane = threadIdx.x & 63;
    int nwaves = (gridDim.x * blockDim.x) >> 6;
    float2 bb = ((const float2*)b1)[lane];
    for (int i = wave; i < NN; i += nwaves) {
        float2 t = upk_bf16(hsb[(size_t)i * 64 + lane]);  // self term
        float ax = t.x, ay = t.y;
        int e = row_ptr[i], s1 = row_ptr[i + 1];
        for (; e + 4 <= s1; e += 4) {
            int sa = col[e + 0], sb = col[e + 1], sc = col[e + 2], sd = col[e + 3];
            unsigned ua = hsb[(size_t)sa * 64 + lane];
            unsigned ub = hsb[(size_t)sb * 64 + lane];
            unsigned uc = hsb[(size_t)sc * 64 + lane];
            unsigned ud = hsb[(size_t)sd * 64 + lane];
            float2 va = upk_bf16(ua), vb = upk_bf16(ub), vc = upk_bf16(uc), vd = upk_bf16(ud);
            ax += va.x + vb.x + vc.x + vd.x;
            ay += va.y + vb.y + vc.y + vd.y;
        }
        for (; e < s1; ++e) {
            float2 v = upk_bf16(hsb[(size_t)col[e] * 64 + lane]);
            ax += v.x;
            ay += v.y;
        }
        float dv = dinv[i];
        float ox = fmaxf(fmaf(ax, dv, bb.x), 0.f);
        float oy = fmaxf(fmaf(ay, dv, bb.y), 0.f);
        h1b[(size_t)i * 64 + lane] = pk_bf16(ox, oy);
    }
}

// ---------------- GEMM2: hs2b = bf16((h1 @ W2) * dinv[row]) ----------------
__global__ __launch_bounds__(256) void gemm2_kernel(const unsigned* __restrict__ h1b,
                                                    const float* __restrict__ W2,
                                                    const float* __restrict__ dinv,
                                                    unsigned* __restrict__ hs2b) {
    __shared__ float wlds[HID][64];   // 32KB zero-padded
    __shared__ float xlds[64][HID];   // 32KB
    int tid = threadIdx.x;
    for (int i = tid; i < HID * 64; i += 256) {
        int k = i / 64, c = i % 64;
        wlds[k][c] = (c < NCLS) ? W2[k * NCLS + c] : 0.f;
    }
    int ct = tid & 15;   // c0 = 4*ct (0..60)
    int rt = tid >> 4;   // 0..15 -> 64 rows
    int c0 = ct * 4;
    int nt = (NN + 63) / 64;
    for (int t = blockIdx.x; t < nt; t += gridDim.x) {
        int rowbase = t * 64;
        __syncthreads();
        // stage h1 (packed bf16) -> f32 LDS: 64 rows x 16 uint4 (8 feats each)
        for (int i = tid; i < 64 * 16; i += 256) {
            int r = i >> 4, q = i & 15;
            int row = rowbase + r;
            uint4 u = (row < NN) ? ((const uint4*)h1b)[(size_t)row * 16 + q]
                                 : make_uint4(0, 0, 0, 0);
            float2 f0 = upk_bf16(u.x), f1 = upk_bf16(u.y);
            float2 f2 = upk_bf16(u.z), f3 = upk_bf16(u.w);
            float* dp = &xlds[r][q * 8];
            ((float4*)dp)[0] = make_float4(f0.x, f0.y, f1.x, f1.y);
            ((float4*)dp)[1] = make_float4(f2.x, f2.y, f3.x, f3.y);
        }
        __syncthreads();
        float acc[4][4];
#pragma unroll
        for (int a = 0; a < 4; ++a)
#pragma unroll
            for (int b = 0; b < 4; ++b) acc[a][b] = 0.f;
        for (int k = 0; k < HID; k += 4) {
            float4 xv[4], wv[4];
#pragma unroll
            for (int a = 0; a < 4; ++a) xv[a] = *(const float4*)&xlds[rt * 4 + a][k];
#pragma unroll
            for (int kk = 0; kk < 4; ++kk) wv[kk] = *(const float4*)&wlds[k + kk][c0];
#pragma unroll
            for (int kk = 0; kk < 4; ++kk) {
                float4 w = wv[kk];
#pragma unroll
                for (int a = 0; a < 4; ++a) {
                    float xs = ((float*)&xv[a])[kk];
                    acc[a][0] = fmaf(xs, w.x, acc[a][0]);
                    acc[a][1] = fmaf(xs, w.y, acc[a][1]);
                    acc[a][2] = fmaf(xs, w.z, acc[a][2]);
                    acc[a][3] = fmaf(xs, w.w, acc[a][3]);
                }
            }
        }
        if (c0 < NCLS) {
#pragma unroll
            for (int a = 0; a < 4; ++a) {
                int row = rowbase + rt * 4 + a;
                if (row < NN) {
                    float dv = dinv[row];
                    uint2 o = make_uint2(pk_bf16(acc[a][0] * dv, acc[a][1] * dv),
                                         pk_bf16(acc[a][2] * dv, acc[a][3] * dv));
                    *(uint2*)(hs2b + (size_t)row * 20 + ct * 2) = o;
                }
            }
        }
    }
}

// ---------------- agg2 + bias + log_softmax ----------------
// one wave per node; lanes 0..19 each own classes 2*lane, 2*lane+1
__global__ __launch_bounds__(256) void agg2_kernel(const unsigned* __restrict__ hs2b,
                                                   const int* __restrict__ row_ptr,
                                                   const int* __restrict__ col,
                                                   const float* __restrict__ dinv,
                                                   const float* __restrict__ b2,
                                                   float* __restrict__ out) {
    int wave = (blockIdx.x * blockDim.x + threadIdx.x) >> 6;
    int lane = threadIdx.x & 63;
    int nwaves = (gridDim.x * blockDim.x) >> 6;
    bool act = lane < (NCLS / 2);
    float2 bb = act ? ((const float2*)b2)[lane] : make_float2(0.f, 0.f);
    for (int i = wave; i < NN; i += nwaves) {
        float ax = 0.f, ay = 0.f;
        if (act) {
            float2 t = upk_bf16(hs2b[(size_t)i * 20 + lane]);  // self term
            ax = t.x; ay = t.y;
        }
        int e = row_ptr[i], s1 = row_ptr[i + 1];
        for (; e + 4 <= s1; e += 4) {
            int sa = col[e + 0], sb = col[e + 1], sc = col[e + 2], sd = col[e + 3];
            if (act) {
                float2 va = upk_bf16(hs2b[(size_t)sa * 20 + lane]);
                float2 vb = upk_bf16(hs2b[(size_t)sb * 20 + lane]);
                float2 vc = upk_bf16(hs2b[(size_t)sc * 20 + lane]);
                float2 vd = upk_bf16(hs2b[(size_t)sd * 20 + lane]);
                ax += va.x + vb.x + vc.x + vd.x;
                ay += va.y + vb.y + vc.y + vd.y;
            }
        }
        for (; e < s1; ++e) {
            int s = col[e];
            if (act) {
                float2 v = upk_bf16(hs2b[(size_t)s * 20 + lane]);
                ax += v.x;
                ay += v.y;
            }
        }
        float dv = dinv[i];
        float lx = fmaf(ax, dv, bb.x);
        float ly = fmaf(ay, dv, bb.y);
        float m = act ? fmaxf(lx, ly) : -INFINITY;
#pragma unroll
        for (int off = 32; off; off >>= 1) m = fmaxf(m, __shfl_xor(m, off));
        float ssum = act ? (expf(lx - m) + expf(ly - m)) : 0.f;
#pragma unroll
        for (int off = 32; off; off >>= 1) ssum += __shfl_xor(ssum, off);
        float ls = logf(ssum);
        if (act) {
            float2 o = make_float2(lx - m - ls, ly - m - ls);
            ((float2*)(out + (size_t)i * NCLS))[lane] = o;
        }
    }
}

extern "C" void kernel_launch(void* const* d_in, const int* in_sizes, int n_in,
                              void* d_out, int out_size, void* d_ws, size_t ws_size,
                              hipStream_t stream) {
    const float* x = (const float*)d_in[0];
    const int* edge_index = (const int*)d_in[1];
    const float* W1 = (const float*)d_in[2];
    const float* b1 = (const float*)d_in[3];
    const float* W2 = (const float*)d_in[4];
    const float* b2 = (const float*)d_in[5];
    float* out = (float*)d_out;
    const int* src = edge_index;          // edge_index[0]
    const int* dst = edge_index + NE;     // edge_index[1]

    char* ws = (char*)d_ws;
    size_t off = 0;
    auto alloc = [&](size_t bytes) -> void* {
        void* p = (void*)(ws + off);
        off += (bytes + 255) & ~(size_t)255;
        return p;
    };
    int* deg = (int*)alloc((size_t)NN * 4);
    int* cursor = (int*)alloc((size_t)NN * 4);
    int* row_ptr = (int*)alloc((size_t)(NN + 1) * 4);
    int* col = (int*)alloc((size_t)NE * 4);
    int* bsum = (int*)alloc((size_t)SCAN_NB * 4);
    float* dinv = (float*)alloc((size_t)NN * 4);
    unsigned* hsb = (unsigned*)alloc((size_t)NN * 64 * 4);   // bf16x2 packed [NN][64]
    unsigned* h1b = (unsigned*)alloc((size_t)NN * 64 * 4);   // bf16x2 packed [NN][64]
    unsigned* hs2b = (unsigned*)alloc((size_t)NN * 20 * 4);  // bf16x2 packed [NN][20]

    hipMemsetAsync(deg, 0, (size_t)NN * 4, stream);
    hipMemsetAsync(cursor, 0, (size_t)NN * 4, stream);

    hist_kernel<<<(NE + 255) / 256, 256, 0, stream>>>(dst, deg);
    dinv_kernel<<<(NN + 255) / 256, 256, 0, stream>>>(deg, dinv);
    scan1_kernel<<<SCAN_NB, 256, 0, stream>>>(deg, row_ptr, bsum);
    scan2_kernel<<<1, 128, 0, stream>>>(bsum);
    scan3_kernel<<<SCAN_NB, 256, 0, stream>>>(row_ptr, bsum);
    scatter_kernel<<<(NE + 255) / 256, 256, 0, stream>>>(src, dst, row_ptr, cursor, col);
    gemm1_kernel<<<512, 256, 0, stream>>>(x, W1, dinv, hsb);
    agg1_kernel<<<2048, 256, 0, stream>>>(hsb, row_ptr, col, dinv, b1, h1b);
    gemm2_kernel<<<512, 256, 0, stream>>>(h1b, W2, dinv, hs2b);
    agg2_kernel<<<2048, 256, 0, stream>>>(hs2b, row_ptr, col, dinv, b2, out);
}